// Round 5
// baseline (1692.018 us; speedup 1.0000x reference)
//
#include <hip/hip_runtime.h>
#include <hip/hip_bf16.h>

// CustomLSTMModel: emb(32000x300 fp32, pad_idx=0) -> LSTM(300->512, 512 steps, B=256, fp32)
//                  -> FC(512->7, fp32). tokens int32; out fp32 [256,7].
// Internal: bf16 MFMA (RNE), fp32 accum/c/biases/FC. absmax ~1e-3 (R2/R4/R5: 9.8e-4).
//
// R11: base = R10 (1550us = R7-equivalent best). R10's neutrality vs R7 proved
// __syncthreads does NOT drain register-destined loads (no memory side-effect) — the
// prefetch always spanned S1. Remaining ~7260cy/step = ~1500 compute + ~600 barriers +
// ~3000+ exposed LLC RTTs. Two independent latency cuts on that chain:
//  1. ALL-WAVE poll + S2a deleted. Each wave polls flags itself (4 concurrent LLC flag
//     loads), starts its h loads on its own observation. Saves the S2a barrier + the
//     wave0->others release hop. LDS x-region hazard still covered by S2b/S3a/S3b/S1.
//  2. x_{t+1} prefetch issued AFTER the h-load issue (fenced: h-issue | prefetch |
//     land). vmcnt retires in issue order, so the h-land waits only the 8 h loads
//     (prefetch stays outstanding) instead of max(h RTT, prefetch remainder).
// Poll stays mid-step after ih (R8/R9 lesson: pre-poll filler absorbs peer skew).
// Carried: 16 groups x 16 batches (N=16), 16 blocks/group x 32 units, 256 blocks x 256
// threads (4 waves), 2 M-tiles/wave A in VGPRs, one B-read feeds both M-tiles, full
// __syncthreads barriers elsewhere, relaxed agent-scope atomics (LLC-coherent, no
// fences), coalesced u64 h writeback via LDS bounce, c in VGPRs, 0xAAAAAAAA poison < 1.

typedef unsigned short ushort_t;
typedef unsigned long long u64_t;
typedef __bf16 bf16x8 __attribute__((ext_vector_type(8)));
typedef unsigned short u16x8v __attribute__((ext_vector_type(8)));
typedef float f32x4 __attribute__((ext_vector_type(4)));

#define U_STRIDE 840   // ushorts: 320 (x incl zero pad) + 512 (h) + 8 pad; row = 1680B
#define HOFF 320
#define SCR_S 36       // scratch row stride in ushorts (72B)

__device__ __forceinline__ float sigmoidf_(float x) { return 1.0f / (1.0f + __expf(-x)); }
__device__ __forceinline__ float tanhf_(float x)    { return 1.0f - 2.0f / (__expf(2.0f * x) + 1.0f); }

__device__ __forceinline__ ushort_t f2bf(float f) {   // RNE; inputs finite
    unsigned u = __builtin_bit_cast(unsigned, f);
    unsigned r = (u + 0x7FFFu + ((u >> 16) & 1u)) >> 16;
    return (ushort_t)r;
}
__device__ __forceinline__ float bf2f(ushort_t u) {
    unsigned v = ((unsigned)u) << 16;
    return __builtin_bit_cast(float, v);
}

// LLC-coherent (cache-bypassing) accessors — relaxed agent atomics, no fences.
__device__ __forceinline__ u64_t g_load64(const u64_t* p) {
    return __hip_atomic_load(p, __ATOMIC_RELAXED, __HIP_MEMORY_SCOPE_AGENT);
}
__device__ __forceinline__ void g_store64(u64_t* p, u64_t v) {
    __hip_atomic_store(p, v, __ATOMIC_RELAXED, __HIP_MEMORY_SCOPE_AGENT);
}
__device__ __forceinline__ int g_load_flag(const int* p) {
    return __hip_atomic_load(p, __ATOMIC_RELAXED, __HIP_MEMORY_SCOPE_AGENT);
}
__device__ __forceinline__ void g_store_flag(int* p, int v) {
    __hip_atomic_store(p, v, __ATOMIC_RELAXED, __HIP_MEMORY_SCOPE_AGENT);
}

__global__ __launch_bounds__(256, 1)
void lstm_fused_kernel(const int* __restrict__ tokens,    // [256][512]
                       const float* __restrict__ emb,     // [32000][300]
                       const float* __restrict__ Wih,     // [2048][300]
                       const float* __restrict__ bih,     // [2048]
                       const float* __restrict__ Whh,     // [2048][512]
                       const float* __restrict__ bhh,     // [2048]
                       const float* __restrict__ Wfc,     // [7][512]
                       const float* __restrict__ bfc,     // [7]
                       float* __restrict__ out,           // [256][7]
                       int* __restrict__ flags,           // [256]
                       ushort_t* __restrict__ hbuf)       // [2][256][512] bf16
{
    __shared__ ushort_t u_lds[16 * U_STRIDE];   // 26880 B (16 batch rows)
    __shared__ ushort_t h_scr[16 * SCR_S];      // 1152 B writeback bounce

    const int tid = threadIdx.x;
    const int bid = blockIdx.x;
    const int g   = bid & 15;      // batch group 0..15 (16 batches; blocks share an XCD)
    const int ib  = bid >> 4;      // block-in-group 0..15 -> unit slice
    const int Bg0 = g * 16;
    const int U0  = ib * 32;       // 32 units per block
    const int lane = tid & 63;
    const int wv   = tid >> 6;     // wave 0..3; wave owns 2 M-tiles (32 gate rows)
    const int lm   = lane & 15;
    const int q    = lane >> 4;

    // ---- preload A-fragments for BOTH M-tiles, fp32 -> bf16 RNE (once) ----
    // M-tile m of wave wv = block gate rows [32*wv + 16*m, +16). rp = unit_local*4 + gate.
    bf16x8 aih[2][10];
    bf16x8 ahh[2][16];
#pragma unroll
    for (int m = 0; m < 2; ++m) {
        const int rp   = 32 * wv + 16 * m + lm;
        const int gi   = rp & 3;
        const int up   = rp >> 2;               // unit_local 0..31
        const int grow = gi * 512 + U0 + up;    // global gate row (i,f,g,o blocks of 512)
#pragma unroll
        for (int kc = 0; kc < 10; ++kc) {
            u16x8v tmp;
#pragma unroll
            for (int j = 0; j < 8; ++j) {
                int col = 32 * kc + 8 * q + j;
                tmp[j] = (col < 300) ? f2bf(Wih[grow * 300 + col]) : (ushort_t)0;
            }
            aih[m][kc] = __builtin_bit_cast(bf16x8, tmp);
        }
#pragma unroll
        for (int kc = 0; kc < 16; ++kc) {
            u16x8v tmp;
#pragma unroll
            for (int j = 0; j < 8; ++j) {
                int col = 32 * kc + 8 * q + j;
                tmp[j] = f2bf(Whh[grow * 512 + col]);
            }
            ahh[m][kc] = __builtin_bit_cast(bf16x8, tmp);
        }
    }

    // ---- per-lane biases (fp32): M-tile m output unit = U0 + 8*wv + 4*m + q ----
    float bias[2][4];
#pragma unroll
    for (int m = 0; m < 2; ++m) {
        const int unit = U0 + 8 * wv + 4 * m + q;
#pragma unroll
        for (int j = 0; j < 4; ++j)
            bias[m][j] = bih[j * 512 + unit] + bhh[j * 512 + unit];
    }

    // ---- init: zero our unit-slice of h parity-0 (h0=0) via bypassing stores ----
    if (tid < 128) {
        int r = tid >> 3;        // batch row 0..15
        int d = tid & 7;         // 8 u64 = 32 units
        g_store64((u64_t*)(hbuf + (size_t)(Bg0 + r) * 512 + U0 + 4 * d), 0ull);
    }
    __syncthreads();             // drains stores before barrier
    if (tid == 0) g_store_flag(&flags[g * 16 + ib], 1);

    const int* myflag = &flags[g * 16 + (lane & 15)];
    float c0 = 0.0f, c1 = 0.0f;

    // ---- x prefetch state: thread handles row xr = tid>>4, elements xln+16k ----
    const int xr  = tid >> 4;        // batch row 0..15
    const int xln = tid & 15;
    const int xb  = Bg0 + xr;
    int tok_cur = tokens[xb * 512 + 0];
    int tok_nxt = tokens[xb * 512 + 1];
    float2 xp[10];
    {
        const float2* s2 = (const float2*)(emb + (size_t)tok_cur * 300);
#pragma unroll
        for (int k = 0; k < 10; ++k) {
            int i = xln + 16 * k;
            if (i < 150) xp[k] = s2[i];
        }
    }

    for (int t = 0; t < 512; ++t) {
        // ---- A: consume prefetched x_t: fp32 -> bf16 pairs -> LDS ----
        {
            unsigned int* dstx = (unsigned int*)(u_lds + xr * U_STRIDE);
            const bool tz = (tok_cur != 0);
#pragma unroll
            for (int k = 0; k < 10; ++k) {     // 160 dwords: 150 data + 10 zero pad
                int i = xln + 16 * k;
                unsigned int v = 0u;
                if (tz && i < 150)
                    v = (unsigned int)f2bf(xp[k].x) | ((unsigned int)f2bf(xp[k].y) << 16);
                dstx[i] = v;
            }
        }
        __syncthreads();   // S1: x staged

        // ---- ih-MFMAs (h-independent, pre-poll filler): one B read feeds both tiles ----
        f32x4 acc0 = {0.f, 0.f, 0.f, 0.f};
        f32x4 acc1 = {0.f, 0.f, 0.f, 0.f};
        const ushort_t* u0 = u_lds + lm * U_STRIDE + 8 * q;   // batches Bg0+0..15
#pragma unroll
        for (int kc = 0; kc < 10; ++kc) {
            bf16x8 b0 = __builtin_bit_cast(bf16x8, *(const u16x8v*)(u0 + 32 * kc));
            acc0 = __builtin_amdgcn_mfma_f32_16x16x32_bf16(aih[0][kc], b0, acc0, 0, 0, 0);
            acc1 = __builtin_amdgcn_mfma_f32_16x16x32_bf16(aih[1][kc], b0, acc1, 0, 0, 0);
        }

        // ---- ALL-WAVE poll (monotonic; 0xAAAAAAAA poison < 1). No S2a barrier:
        //      each wave proceeds to its h loads on its own observation. ----
        {
            const int target = t + 1;
            while (true) {
                int v = g_load_flag(myflag);
                if (__all(v >= target)) break;
                __builtin_amdgcn_s_sleep(1);
            }
            asm volatile("" ::: "memory");   // no reordering of h loads above the poll
        }

        // ---- E: issue h loads | fence | issue x_{t+1} prefetch | fence | land h ----
        {
            const int hr  = tid >> 4;       // batch row 0..15
            const int hln = tid & 15;
            const u64_t* hsrc = (const u64_t*)(hbuf + (size_t)(t & 1) * (256 * 512)
                                               + (size_t)(Bg0 + hr) * 512);
            u64_t htmp[8];
#pragma unroll
            for (int k = 0; k < 8; ++k) htmp[k] = g_load64(hsrc + hln + 16 * k);
            asm volatile("" ::: "memory");  // pin: prefetch issues AFTER h loads (FIFO vmcnt)

            // prefetch x_{t+1}: newest in vmcnt FIFO -> h-land below doesn't wait it
            tok_cur = tok_nxt;
            const float2* s2 = (const float2*)(emb + (size_t)tok_cur * 300);
#pragma unroll
            for (int k = 0; k < 10; ++k) {
                int i = xln + 16 * k;
                if (i < 150) xp[k] = s2[i];
            }
            int t2 = (t + 2 < 512) ? (t + 2) : 511;
            tok_nxt = tokens[xb * 512 + t2];
            asm volatile("" ::: "memory");  // pin: land stays after prefetch issue

            u64_t* dsth = (u64_t*)(u_lds + hr * U_STRIDE + HOFF);
#pragma unroll
            for (int k = 0; k < 8; ++k) dsth[hln + 16 * k] = htmp[k];
        }
        __syncthreads();   // S2b: h staged (register loads in flight are NOT drained)

        // ---- hh-MFMAs: one B read feeds both M-tiles ----
#pragma unroll
        for (int kc = 0; kc < 16; ++kc) {
            bf16x8 b0 = __builtin_bit_cast(bf16x8, *(const u16x8v*)(u0 + HOFF + 32 * kc));
            acc0 = __builtin_amdgcn_mfma_f32_16x16x32_bf16(ahh[0][kc], b0, acc0, 0, 0, 0);
            acc1 = __builtin_amdgcn_mfma_f32_16x16x32_bf16(ahh[1][kc], b0, acc1, 0, 0, 0);
        }

        // ---- elementwise LSTM (lane-local: acc_m = i,f,g,o of unit 8wv+4m+q) ----
        {
            {
                float ig = sigmoidf_(acc0.x + bias[0][0]);
                float fg = sigmoidf_(acc0.y + bias[0][1]);
                float gg = tanhf_(acc0.z + bias[0][2]);
                float og = sigmoidf_(acc0.w + bias[0][3]);
                c0 = fg * c0 + ig * gg;
                h_scr[lm * SCR_S + 8 * wv + q] = f2bf(og * tanhf_(c0));
            }
            {
                float ig = sigmoidf_(acc1.x + bias[1][0]);
                float fg = sigmoidf_(acc1.y + bias[1][1]);
                float gg = tanhf_(acc1.z + bias[1][2]);
                float og = sigmoidf_(acc1.w + bias[1][3]);
                c1 = fg * c1 + ig * gg;
                h_scr[lm * SCR_S + 8 * wv + 4 + q] = f2bf(og * tanhf_(c1));
            }
        }
        __syncthreads();   // S3a: scratch complete (lgkmcnt drain)

        // ---- coalesced bypassing writeback: 128 x u64 (64B-contiguous per row) ----
        if (tid < 128) {
            const int r = tid >> 3;    // batch row 0..15
            const int d = tid & 7;     // u64 index 0..7 (4 units each)
            u64_t v = *(const u64_t*)((const char*)h_scr + r * (SCR_S * 2) + d * 8);
            ushort_t* hdst = hbuf + (size_t)((t + 1) & 1) * (256 * 512);
            g_store64((u64_t*)(hdst + (size_t)(Bg0 + r) * 512 + U0 + 4 * d), v);
        }
        __syncthreads();   // S3b: store drain -> h at LLC before publish
        if (tid == 0) g_store_flag(&flags[g * 16 + ib], t + 2);
    }

    // ---- wait group done (513), then FC: block handles batch Bg0+ib ----
    if (wv == 0) {
        while (true) {
            int v = g_load_flag(myflag);
            if (__all(v >= 513)) break;
            __builtin_amdgcn_s_sleep(1);
        }
        asm volatile("" ::: "memory");
    }
    __syncthreads();

    {
        const int bb = Bg0 + ib;
        const ushort_t* hrow = hbuf + (size_t)bb * 512;  // final h in parity 0
        u64_t h0 = g_load64((const u64_t*)(hrow + lane * 8));
        u64_t h1 = g_load64((const u64_t*)(hrow + lane * 8 + 4));
        float hv[8];
#pragma unroll
        for (int j = 0; j < 4; ++j) hv[j]     = bf2f((ushort_t)(h0 >> (16 * j)));
#pragma unroll
        for (int j = 0; j < 4; ++j) hv[4 + j] = bf2f((ushort_t)(h1 >> (16 * j)));
#pragma unroll
        for (int oo = 0; oo < 2; ++oo) {
            int o = wv + 4 * oo;       // waves 0..3 -> o {0,4},{1,5},{2,6},{3}
            if (o < 7) {
                f32x4 w0 = *(const f32x4*)(Wfc + o * 512 + lane * 8);
                f32x4 w1 = *(const f32x4*)(Wfc + o * 512 + lane * 8 + 4);
                float s = hv[0] * w0.x + hv[1] * w0.y + hv[2] * w0.z + hv[3] * w0.w
                        + hv[4] * w1.x + hv[5] * w1.y + hv[6] * w1.z + hv[7] * w1.w;
#pragma unroll
                for (int sh = 32; sh >= 1; sh >>= 1) s += __shfl_down(s, sh);
                if (lane == 0)
                    out[bb * 7 + o] = s + bfc[o];
            }
        }
    }
}

extern "C" void kernel_launch(void* const* d_in, const int* in_sizes, int n_in,
                              void* d_out, int out_size, void* d_ws, size_t ws_size,
                              hipStream_t stream) {
    const int* tokens = (const int*)d_in[0];
    const float* emb  = (const float*)d_in[1];
    const float* Wih  = (const float*)d_in[2];
    const float* bih  = (const float*)d_in[3];
    const float* Whh  = (const float*)d_in[4];
    const float* bhh  = (const float*)d_in[5];
    const float* Wfc  = (const float*)d_in[6];
    const float* bfc  = (const float*)d_in[7];

    int* flags      = (int*)d_ws;                       // 256 ints (group g: flags[16g..16g+15])
    ushort_t* hbuf  = (ushort_t*)((char*)d_ws + 1024);  // [2][256][512] bf16 = 512 KiB

    lstm_fused_kernel<<<dim3(256), dim3(256), 0, stream>>>(
        tokens, emb, Wih, bih, Whh, bhh, Wfc, bfc,
        (float*)d_out, flags, hbuf);
}

// Round 6
// 1682.332 us; speedup vs baseline: 1.0058x; 1.0058x over previous
//
#include <hip/hip_runtime.h>
#include <hip/hip_bf16.h>

// CustomLSTMModel: emb(32000x300 fp32, pad_idx=0) -> LSTM(300->512, 512 steps, B=256, fp32)
//                  -> FC(512->7, fp32). tokens int32; out fp32 [256,7].
// Internal: bf16 MFMA (RNE), fp32 accum/c/biases/FC. absmax ~1e-3 (R2/R4/R5: 9.8e-4).
//
// R12: base = R10 (1550us best). Attack the PUBLISH side of the inter-block chain
// structurally (accounted work ~2800cy/step vs measured 7264cy -> the gap lives in
// barriers/bounce/straggler skew, not in load scheduling):
//  - A-row remap: unit = U0 + 8*wv + 2*q + m (was 4*m + q). Pure relabeling (same MFMA
//    sequence); a lane's two M-tile h-outputs are now ADJACENT units.
//  - Direct h writeback: each lane packs its 2 bf16 h values into one u32 and stores
//    straight to hbuf. Deletes h_scr, S3a, the tid<128 bounce writeback, and S3b.
//  - Per-wave publish: elementwise -> store -> own-wave vmcnt(0) -> own wave-flag
//    (64 flags/group). Fast waves publish ~2 barriers earlier; straggler skew shrinks.
//  - Per-wave poll of all 64 wave-flags (lane l <-> flag l, one load/iter). S2a gone.
//  Barriers/step: 5 -> 2 (S1, S2b). Hazards verified: a wave at A(t+1) has passed
//  S2b(t) so all ih(t) x-reads done; stage(t+1) gated by S1(t+1); parity overwrite
//  excluded by the flag chain (publisher of h_{t+2} saw all waves' t+1 flags, which
//  follow their h_t loads).
// Carried from R10: 16 groups x 16 batches (N=16), 16 blocks/group x 32 units, 256
// blocks x 256 threads (4 waves), 2 M-tiles/wave A in VGPRs, one B-read feeds both
// M-tiles, prefetch issued after S1, relaxed agent-scope atomics (LLC-coherent, no
// fences), c in VGPRs, 0xAAAAAAAA poison < 1 monotonic flags.

typedef unsigned short ushort_t;
typedef unsigned long long u64_t;
typedef __bf16 bf16x8 __attribute__((ext_vector_type(8)));
typedef unsigned short u16x8v __attribute__((ext_vector_type(8)));
typedef float f32x4 __attribute__((ext_vector_type(4)));

#define U_STRIDE 840   // ushorts: 320 (x incl zero pad) + 512 (h) + 8 pad; row = 1680B
#define HOFF 320

__device__ __forceinline__ float sigmoidf_(float x) { return 1.0f / (1.0f + __expf(-x)); }
__device__ __forceinline__ float tanhf_(float x)    { return 1.0f - 2.0f / (__expf(2.0f * x) + 1.0f); }

__device__ __forceinline__ ushort_t f2bf(float f) {   // RNE; inputs finite
    unsigned u = __builtin_bit_cast(unsigned, f);
    unsigned r = (u + 0x7FFFu + ((u >> 16) & 1u)) >> 16;
    return (ushort_t)r;
}
__device__ __forceinline__ float bf2f(ushort_t u) {
    unsigned v = ((unsigned)u) << 16;
    return __builtin_bit_cast(float, v);
}

// LLC-coherent (cache-bypassing) accessors — relaxed agent atomics, no fences.
__device__ __forceinline__ u64_t g_load64(const u64_t* p) {
    return __hip_atomic_load(p, __ATOMIC_RELAXED, __HIP_MEMORY_SCOPE_AGENT);
}
__device__ __forceinline__ void g_store64(u64_t* p, u64_t v) {
    __hip_atomic_store(p, v, __ATOMIC_RELAXED, __HIP_MEMORY_SCOPE_AGENT);
}
__device__ __forceinline__ void g_store32(unsigned int* p, unsigned int v) {
    __hip_atomic_store(p, v, __ATOMIC_RELAXED, __HIP_MEMORY_SCOPE_AGENT);
}
__device__ __forceinline__ int g_load_flag(const int* p) {
    return __hip_atomic_load(p, __ATOMIC_RELAXED, __HIP_MEMORY_SCOPE_AGENT);
}
__device__ __forceinline__ void g_store_flag(int* p, int v) {
    __hip_atomic_store(p, v, __ATOMIC_RELAXED, __HIP_MEMORY_SCOPE_AGENT);
}

__global__ __launch_bounds__(256, 1)
void lstm_fused_kernel(const int* __restrict__ tokens,    // [256][512]
                       const float* __restrict__ emb,     // [32000][300]
                       const float* __restrict__ Wih,     // [2048][300]
                       const float* __restrict__ bih,     // [2048]
                       const float* __restrict__ Whh,     // [2048][512]
                       const float* __restrict__ bhh,     // [2048]
                       const float* __restrict__ Wfc,     // [7][512]
                       const float* __restrict__ bfc,     // [7]
                       float* __restrict__ out,           // [256][7]
                       int* __restrict__ flags,           // [1024]: group g -> [g*64, g*64+64)
                       ushort_t* __restrict__ hbuf)       // [2][256][512] bf16
{
    __shared__ ushort_t u_lds[16 * U_STRIDE];   // 26880 B (16 batch rows)

    const int tid = threadIdx.x;
    const int bid = blockIdx.x;
    const int g   = bid & 15;      // batch group 0..15 (16 batches; blocks share an XCD)
    const int ib  = bid >> 4;      // block-in-group 0..15 -> unit slice
    const int Bg0 = g * 16;
    const int U0  = ib * 32;       // 32 units per block
    const int lane = tid & 63;
    const int wv   = tid >> 6;     // wave 0..3; wave owns 2 M-tiles (32 gate rows)
    const int lm   = lane & 15;
    const int q    = lane >> 4;

    // ---- preload A-fragments for BOTH M-tiles, fp32 -> bf16 RNE (once) ----
    // R12 remap: A-load row lm of M-tile m -> gate (lm&3) of unit U0+8wv+2*(lm>>2)+m.
    // (C/D row 4q+j then lands gate j of unit U0+8wv+2q+m: lane's two h are adjacent.)
    bf16x8 aih[2][10];
    bf16x8 ahh[2][16];
#pragma unroll
    for (int m = 0; m < 2; ++m) {
        const int grow = (lm & 3) * 512 + U0 + 8 * wv + 2 * (lm >> 2) + m;
#pragma unroll
        for (int kc = 0; kc < 10; ++kc) {
            u16x8v tmp;
#pragma unroll
            for (int j = 0; j < 8; ++j) {
                int col = 32 * kc + 8 * q + j;
                tmp[j] = (col < 300) ? f2bf(Wih[grow * 300 + col]) : (ushort_t)0;
            }
            aih[m][kc] = __builtin_bit_cast(bf16x8, tmp);
        }
#pragma unroll
        for (int kc = 0; kc < 16; ++kc) {
            u16x8v tmp;
#pragma unroll
            for (int j = 0; j < 8; ++j) {
                int col = 32 * kc + 8 * q + j;
                tmp[j] = f2bf(Whh[grow * 512 + col]);
            }
            ahh[m][kc] = __builtin_bit_cast(bf16x8, tmp);
        }
    }

    // ---- per-lane biases (fp32): M-tile m output unit = U0 + 8*wv + 2*q + m ----
    float bias[2][4];
#pragma unroll
    for (int m = 0; m < 2; ++m) {
        const int unit = U0 + 8 * wv + 2 * q + m;
#pragma unroll
        for (int j = 0; j < 4; ++j)
            bias[m][j] = bih[j * 512 + unit] + bhh[j * 512 + unit];
    }

    // ---- init: zero our unit-slice of h parity-0 (h0=0) via bypassing stores ----
    if (tid < 128) {
        int r = tid >> 3;        // batch row 0..15
        int d = tid & 7;         // 8 u64 = 32 units
        g_store64((u64_t*)(hbuf + (size_t)(Bg0 + r) * 512 + U0 + 4 * d), 0ull);
    }
    __syncthreads();             // drains zero stores (outside hot loop)
    if (lane == 0) g_store_flag(&flags[g * 64 + ib * 4 + wv], 1);

    const int* myflag = &flags[g * 64 + lane];   // lane l polls wave-flag l (64 total)
    int* pubflag = &flags[g * 64 + ib * 4 + wv];
    float c0 = 0.0f, c1 = 0.0f;

    // ---- x prefetch state: thread handles row xr = tid>>4, elements xln+16k ----
    const int xr  = tid >> 4;        // batch row 0..15
    const int xln = tid & 15;
    const int xb  = Bg0 + xr;
    int tok_cur = tokens[xb * 512 + 0];
    int tok_nxt = tokens[xb * 512 + 1];
    float2 xp[10];
    {
        const float2* s2 = (const float2*)(emb + (size_t)tok_cur * 300);
#pragma unroll
        for (int k = 0; k < 10; ++k) {
            int i = xln + 16 * k;
            if (i < 150) xp[k] = s2[i];
        }
    }

    for (int t = 0; t < 512; ++t) {
        // ---- A: consume prefetched x_t: fp32 -> bf16 pairs -> LDS ----
        {
            unsigned int* dstx = (unsigned int*)(u_lds + xr * U_STRIDE);
            const bool tz = (tok_cur != 0);
#pragma unroll
            for (int k = 0; k < 10; ++k) {     // 160 dwords: 150 data + 10 zero pad
                int i = xln + 16 * k;
                unsigned int v = 0u;
                if (tz && i < 150)
                    v = (unsigned int)f2bf(xp[k].x) | ((unsigned int)f2bf(xp[k].y) << 16);
                dstx[i] = v;
            }
        }
        __syncthreads();   // S1: x staged

        // ---- issue prefetch for x_{t+1} (R10 position: after S1) ----
        {
            tok_cur = tok_nxt;
            const float2* s2 = (const float2*)(emb + (size_t)tok_cur * 300);
#pragma unroll
            for (int k = 0; k < 10; ++k) {
                int i = xln + 16 * k;
                if (i < 150) xp[k] = s2[i];
            }
            int t2 = (t + 2 < 512) ? (t + 2) : 511;
            tok_nxt = tokens[xb * 512 + t2];
        }

        // ---- ih-MFMAs (h-independent, pre-poll filler): one B read feeds both tiles ----
        f32x4 acc0 = {0.f, 0.f, 0.f, 0.f};
        f32x4 acc1 = {0.f, 0.f, 0.f, 0.f};
        const ushort_t* u0 = u_lds + lm * U_STRIDE + 8 * q;   // batches Bg0+0..15
#pragma unroll
        for (int kc = 0; kc < 10; ++kc) {
            bf16x8 b0 = __builtin_bit_cast(bf16x8, *(const u16x8v*)(u0 + 32 * kc));
            acc0 = __builtin_amdgcn_mfma_f32_16x16x32_bf16(aih[0][kc], b0, acc0, 0, 0, 0);
            acc1 = __builtin_amdgcn_mfma_f32_16x16x32_bf16(aih[1][kc], b0, acc1, 0, 0, 0);
        }

        // ---- per-wave poll of all 64 wave-flags (monotonic; poison < 1) ----
        {
            const int target = t + 1;
            while (true) {
                int v = g_load_flag(myflag);
                if (__all(v >= target)) break;
                __builtin_amdgcn_s_sleep(1);
            }
            asm volatile("" ::: "memory");   // no reordering of h loads above the poll
        }

        // ---- stage h_t via bypassing u64 loads -> LDS (128 u64 = 1 KB per row) ----
        {
            const int r  = tid >> 4;       // batch row 0..15
            const int ln = tid & 15;
            const u64_t* hsrc = (const u64_t*)(hbuf + (size_t)(t & 1) * (256 * 512)
                                               + (size_t)(Bg0 + r) * 512);
            u64_t* dsth = (u64_t*)(u_lds + r * U_STRIDE + HOFF);
            u64_t tmp[8];
#pragma unroll
            for (int k = 0; k < 8; ++k) tmp[k] = g_load64(hsrc + ln + 16 * k);
#pragma unroll
            for (int k = 0; k < 8; ++k) dsth[ln + 16 * k] = tmp[k];
        }
        __syncthreads();   // S2b: h staged (drains h loads + in-flight prefetch)

        // ---- hh-MFMAs: one B read feeds both M-tiles ----
#pragma unroll
        for (int kc = 0; kc < 16; ++kc) {
            bf16x8 b0 = __builtin_bit_cast(bf16x8, *(const u16x8v*)(u0 + HOFF + 32 * kc));
            acc0 = __builtin_amdgcn_mfma_f32_16x16x32_bf16(ahh[0][kc], b0, acc0, 0, 0, 0);
            acc1 = __builtin_amdgcn_mfma_f32_16x16x32_bf16(ahh[1][kc], b0, acc1, 0, 0, 0);
        }

        // ---- elementwise LSTM + direct packed h store (units U0+8wv+2q, +1) ----
        {
            float h0v, h1v;
            {
                float ig = sigmoidf_(acc0.x + bias[0][0]);
                float fg = sigmoidf_(acc0.y + bias[0][1]);
                float gg = tanhf_(acc0.z + bias[0][2]);
                float og = sigmoidf_(acc0.w + bias[0][3]);
                c0 = fg * c0 + ig * gg;
                h0v = og * tanhf_(c0);
            }
            {
                float ig = sigmoidf_(acc1.x + bias[1][0]);
                float fg = sigmoidf_(acc1.y + bias[1][1]);
                float gg = tanhf_(acc1.z + bias[1][2]);
                float og = sigmoidf_(acc1.w + bias[1][3]);
                c1 = fg * c1 + ig * gg;
                h1v = og * tanhf_(c1);
            }
            unsigned int hp = (unsigned int)f2bf(h0v) | ((unsigned int)f2bf(h1v) << 16);
            ushort_t* hdst = hbuf + (size_t)((t + 1) & 1) * (256 * 512);
            g_store32((unsigned int*)(hdst + (size_t)(Bg0 + lm) * 512 + U0 + 8 * wv + 2 * q),
                      hp);
        }
        // ---- per-wave publish: drain own stores (prefetch is old/complete), flag ----
        asm volatile("s_waitcnt vmcnt(0)" ::: "memory");
        if (lane == 0) g_store_flag(pubflag, t + 2);
    }

    // ---- wait group done (513), then FC: block handles batch Bg0+ib ----
    {
        while (true) {
            int v = g_load_flag(myflag);
            if (__all(v >= 513)) break;
            __builtin_amdgcn_s_sleep(1);
        }
        asm volatile("" ::: "memory");
    }

    {
        const int bb = Bg0 + ib;
        const ushort_t* hrow = hbuf + (size_t)bb * 512;  // final h in parity 0
        u64_t h0 = g_load64((const u64_t*)(hrow + lane * 8));
        u64_t h1 = g_load64((const u64_t*)(hrow + lane * 8 + 4));
        float hv[8];
#pragma unroll
        for (int j = 0; j < 4; ++j) hv[j]     = bf2f((ushort_t)(h0 >> (16 * j)));
#pragma unroll
        for (int j = 0; j < 4; ++j) hv[4 + j] = bf2f((ushort_t)(h1 >> (16 * j)));
#pragma unroll
        for (int oo = 0; oo < 2; ++oo) {
            int o = wv + 4 * oo;       // waves 0..3 -> o {0,4},{1,5},{2,6},{3}
            if (o < 7) {
                f32x4 w0 = *(const f32x4*)(Wfc + o * 512 + lane * 8);
                f32x4 w1 = *(const f32x4*)(Wfc + o * 512 + lane * 8 + 4);
                float s = hv[0] * w0.x + hv[1] * w0.y + hv[2] * w0.z + hv[3] * w0.w
                        + hv[4] * w1.x + hv[5] * w1.y + hv[6] * w1.z + hv[7] * w1.w;
#pragma unroll
                for (int sh = 32; sh >= 1; sh >>= 1) s += __shfl_down(s, sh);
                if (lane == 0)
                    out[bb * 7 + o] = s + bfc[o];
            }
        }
    }
}

extern "C" void kernel_launch(void* const* d_in, const int* in_sizes, int n_in,
                              void* d_out, int out_size, void* d_ws, size_t ws_size,
                              hipStream_t stream) {
    const int* tokens = (const int*)d_in[0];
    const float* emb  = (const float*)d_in[1];
    const float* Wih  = (const float*)d_in[2];
    const float* bih  = (const float*)d_in[3];
    const float* Whh  = (const float*)d_in[4];
    const float* bhh  = (const float*)d_in[5];
    const float* Wfc  = (const float*)d_in[6];
    const float* bfc  = (const float*)d_in[7];

    int* flags      = (int*)d_ws;                       // 1024 ints: 64 wave-flags/group
    ushort_t* hbuf  = (ushort_t*)((char*)d_ws + 4096);  // [2][256][512] bf16 = 512 KiB

    lstm_fused_kernel<<<dim3(256), dim3(256), 0, stream>>>(
        tokens, emb, Wih, bih, Whh, bhh, Wfc, bfc,
        (float*)d_out, flags, hbuf);
}

// Round 7
// 1615.692 us; speedup vs baseline: 1.0472x; 1.0412x over previous
//
#include <hip/hip_runtime.h>
#include <hip/hip_bf16.h>

// CustomLSTMModel: emb(32000x300 fp32, pad_idx=0) -> LSTM(300->512, 512 steps, B=256, fp32)
//                  -> FC(512->7, fp32). tokens int32; out fp32 [256,7].
// Internal: bf16 MFMA (RNE), fp32 accum/c/biases/FC. absmax ~1e-3 (R2/R4/R5: 9.8e-4).
//
// R13: base = R10 (1550us best). R12 post-mortem: per-lane 4B h-stores caused 2x HBM
// write amplification (WRITE 176->318MB) -> the u64 LDS-bounce writeback is load-bearing.
// Model now closes: agent-scope atomics are LLC-routed, so the step chain carries TWO
// serial LLC RTTs (~600cy each): flag-poll observe + h load. Flags are monotonic and
// peers publish a full step ahead -> the poll's first load almost always passes; its RTT
// is pure exposed latency. ONE pure-additive change:
//  - wave0 ISSUES the flag load right after S1 (non-blocking; prefetch-issue + ih
//    ~500cy sit between issue and use), poll checks the preloaded value first and only
//    falls back to the loop if peers are behind. vmcnt FIFO: flag load is oldest, check
//    drains only it, prefetch stays in flight. No barrier/order/publish changes.
// Carried from R10: 16 groups x 16 batches (N=16), 16 blocks/group x 32 units, 256
// blocks x 256 threads (4 waves), 2 M-tiles/wave A in VGPRs, one B-read feeds both
// M-tiles, prefetch issued after S1, full __syncthreads barriers, relaxed agent-scope
// atomics (LLC-coherent, no fences), coalesced u64 h writeback via LDS bounce, c in
// VGPRs, wave-0-only poll, 0xAAAAAAAA poison < 1 monotonic flags.

typedef unsigned short ushort_t;
typedef unsigned long long u64_t;
typedef __bf16 bf16x8 __attribute__((ext_vector_type(8)));
typedef unsigned short u16x8v __attribute__((ext_vector_type(8)));
typedef float f32x4 __attribute__((ext_vector_type(4)));

#define U_STRIDE 840   // ushorts: 320 (x incl zero pad) + 512 (h) + 8 pad; row = 1680B
#define HOFF 320
#define SCR_S 36       // scratch row stride in ushorts (72B)

__device__ __forceinline__ float sigmoidf_(float x) { return 1.0f / (1.0f + __expf(-x)); }
__device__ __forceinline__ float tanhf_(float x)    { return 1.0f - 2.0f / (__expf(2.0f * x) + 1.0f); }

__device__ __forceinline__ ushort_t f2bf(float f) {   // RNE; inputs finite
    unsigned u = __builtin_bit_cast(unsigned, f);
    unsigned r = (u + 0x7FFFu + ((u >> 16) & 1u)) >> 16;
    return (ushort_t)r;
}
__device__ __forceinline__ float bf2f(ushort_t u) {
    unsigned v = ((unsigned)u) << 16;
    return __builtin_bit_cast(float, v);
}

// LLC-coherent (cache-bypassing) accessors — relaxed agent atomics, no fences.
__device__ __forceinline__ u64_t g_load64(const u64_t* p) {
    return __hip_atomic_load(p, __ATOMIC_RELAXED, __HIP_MEMORY_SCOPE_AGENT);
}
__device__ __forceinline__ void g_store64(u64_t* p, u64_t v) {
    __hip_atomic_store(p, v, __ATOMIC_RELAXED, __HIP_MEMORY_SCOPE_AGENT);
}
__device__ __forceinline__ int g_load_flag(const int* p) {
    return __hip_atomic_load(p, __ATOMIC_RELAXED, __HIP_MEMORY_SCOPE_AGENT);
}
__device__ __forceinline__ void g_store_flag(int* p, int v) {
    __hip_atomic_store(p, v, __ATOMIC_RELAXED, __HIP_MEMORY_SCOPE_AGENT);
}

__global__ __launch_bounds__(256, 1)
void lstm_fused_kernel(const int* __restrict__ tokens,    // [256][512]
                       const float* __restrict__ emb,     // [32000][300]
                       const float* __restrict__ Wih,     // [2048][300]
                       const float* __restrict__ bih,     // [2048]
                       const float* __restrict__ Whh,     // [2048][512]
                       const float* __restrict__ bhh,     // [2048]
                       const float* __restrict__ Wfc,     // [7][512]
                       const float* __restrict__ bfc,     // [7]
                       float* __restrict__ out,           // [256][7]
                       int* __restrict__ flags,           // [256]
                       ushort_t* __restrict__ hbuf)       // [2][256][512] bf16
{
    __shared__ ushort_t u_lds[16 * U_STRIDE];   // 26880 B (16 batch rows)
    __shared__ ushort_t h_scr[16 * SCR_S];      // 1152 B writeback bounce

    const int tid = threadIdx.x;
    const int bid = blockIdx.x;
    const int g   = bid & 15;      // batch group 0..15 (16 batches; blocks share an XCD)
    const int ib  = bid >> 4;      // block-in-group 0..15 -> unit slice
    const int Bg0 = g * 16;
    const int U0  = ib * 32;       // 32 units per block
    const int lane = tid & 63;
    const int wv   = tid >> 6;     // wave 0..3; wave owns 2 M-tiles (32 gate rows)
    const int lm   = lane & 15;
    const int q    = lane >> 4;

    // ---- preload A-fragments for BOTH M-tiles, fp32 -> bf16 RNE (once) ----
    // M-tile m of wave wv = block gate rows [32*wv + 16*m, +16). rp = unit_local*4 + gate.
    bf16x8 aih[2][10];
    bf16x8 ahh[2][16];
#pragma unroll
    for (int m = 0; m < 2; ++m) {
        const int rp   = 32 * wv + 16 * m + lm;
        const int gi   = rp & 3;
        const int up   = rp >> 2;               // unit_local 0..31
        const int grow = gi * 512 + U0 + up;    // global gate row (i,f,g,o blocks of 512)
#pragma unroll
        for (int kc = 0; kc < 10; ++kc) {
            u16x8v tmp;
#pragma unroll
            for (int j = 0; j < 8; ++j) {
                int col = 32 * kc + 8 * q + j;
                tmp[j] = (col < 300) ? f2bf(Wih[grow * 300 + col]) : (ushort_t)0;
            }
            aih[m][kc] = __builtin_bit_cast(bf16x8, tmp);
        }
#pragma unroll
        for (int kc = 0; kc < 16; ++kc) {
            u16x8v tmp;
#pragma unroll
            for (int j = 0; j < 8; ++j) {
                int col = 32 * kc + 8 * q + j;
                tmp[j] = f2bf(Whh[grow * 512 + col]);
            }
            ahh[m][kc] = __builtin_bit_cast(bf16x8, tmp);
        }
    }

    // ---- per-lane biases (fp32): M-tile m output unit = U0 + 8*wv + 4*m + q ----
    float bias[2][4];
#pragma unroll
    for (int m = 0; m < 2; ++m) {
        const int unit = U0 + 8 * wv + 4 * m + q;
#pragma unroll
        for (int j = 0; j < 4; ++j)
            bias[m][j] = bih[j * 512 + unit] + bhh[j * 512 + unit];
    }

    // ---- init: zero our unit-slice of h parity-0 (h0=0) via bypassing stores ----
    if (tid < 128) {
        int r = tid >> 3;        // batch row 0..15
        int d = tid & 7;         // 8 u64 = 32 units
        g_store64((u64_t*)(hbuf + (size_t)(Bg0 + r) * 512 + U0 + 4 * d), 0ull);
    }
    __syncthreads();             // drains stores before barrier
    if (tid == 0) g_store_flag(&flags[g * 16 + ib], 1);

    const int* myflag = &flags[g * 16 + (lane & 15)];
    float c0 = 0.0f, c1 = 0.0f;

    // ---- x prefetch state: thread handles row xr = tid>>4, elements xln+16k ----
    const int xr  = tid >> 4;        // batch row 0..15
    const int xln = tid & 15;
    const int xb  = Bg0 + xr;
    int tok_cur = tokens[xb * 512 + 0];
    int tok_nxt = tokens[xb * 512 + 1];
    float2 xp[10];
    {
        const float2* s2 = (const float2*)(emb + (size_t)tok_cur * 300);
#pragma unroll
        for (int k = 0; k < 10; ++k) {
            int i = xln + 16 * k;
            if (i < 150) xp[k] = s2[i];
        }
    }

    for (int t = 0; t < 512; ++t) {
        // ---- consume prefetched x_t: fp32 -> bf16 pairs -> LDS ----
        {
            unsigned int* dstx = (unsigned int*)(u_lds + xr * U_STRIDE);
            const bool tz = (tok_cur != 0);
#pragma unroll
            for (int k = 0; k < 10; ++k) {     // 160 dwords: 150 data + 10 zero pad
                int i = xln + 16 * k;
                unsigned int v = 0u;
                if (tz && i < 150)
                    v = (unsigned int)f2bf(xp[k].x) | ((unsigned int)f2bf(xp[k].y) << 16);
                dstx[i] = v;
            }
        }
        __syncthreads();   // S1: x staged

        // ---- R13: wave0 ISSUES flag load now (oldest in vmcnt FIFO); checked after ih.
        //      ~500cy of prefetch-issue + ih hide its LLC RTT. ----
        int v0 = 0;
        if (wv == 0) v0 = g_load_flag(myflag);

        // ---- issue prefetch for x_{t+1} (R10 position: after S1) ----
        {
            tok_cur = tok_nxt;
            const float2* s2 = (const float2*)(emb + (size_t)tok_cur * 300);
#pragma unroll
            for (int k = 0; k < 10; ++k) {
                int i = xln + 16 * k;
                if (i < 150) xp[k] = s2[i];
            }
            int t2 = (t + 2 < 512) ? (t + 2) : 511;
            tok_nxt = tokens[xb * 512 + t2];
        }

        // ---- ih-MFMAs (h-independent, pre-poll filler): one B read feeds both tiles ----
        f32x4 acc0 = {0.f, 0.f, 0.f, 0.f};
        f32x4 acc1 = {0.f, 0.f, 0.f, 0.f};
        const ushort_t* u0 = u_lds + lm * U_STRIDE + 8 * q;   // batches Bg0+0..15
#pragma unroll
        for (int kc = 0; kc < 10; ++kc) {
            bf16x8 b0 = __builtin_bit_cast(bf16x8, *(const u16x8v*)(u0 + 32 * kc));
            acc0 = __builtin_amdgcn_mfma_f32_16x16x32_bf16(aih[0][kc], b0, acc0, 0, 0, 0);
            acc1 = __builtin_amdgcn_mfma_f32_16x16x32_bf16(aih[1][kc], b0, acc1, 0, 0, 0);
        }

        // ---- wave 0 poll: preloaded value first (usually passes: peers published a
        //      full step ago), fallback loop otherwise. Monotonic; poison < 1. ----
        if (wv == 0) {
            const int target = t + 1;
            if (!__all(v0 >= target)) {
                while (true) {
                    int v = g_load_flag(myflag);
                    if (__all(v >= target)) break;
                    __builtin_amdgcn_s_sleep(1);
                }
            }
            asm volatile("" ::: "memory");   // no reordering of h loads above the poll
        }
        __syncthreads();   // S2a: release all waves

        // ---- stage h_t via bypassing u64 loads -> LDS (128 u64 = 1 KB per row) ----
        {
            const int r  = tid >> 4;       // batch row 0..15
            const int ln = tid & 15;
            const u64_t* hsrc = (const u64_t*)(hbuf + (size_t)(t & 1) * (256 * 512)
                                               + (size_t)(Bg0 + r) * 512);
            u64_t* dsth = (u64_t*)(u_lds + r * U_STRIDE + HOFF);
            u64_t tmp[8];
#pragma unroll
            for (int k = 0; k < 8; ++k) tmp[k] = g_load64(hsrc + ln + 16 * k);
#pragma unroll
            for (int k = 0; k < 8; ++k) dsth[ln + 16 * k] = tmp[k];
        }
        __syncthreads();   // S2b: h staged (drains h loads + in-flight prefetch)

        // ---- hh-MFMAs: one B read feeds both M-tiles ----
#pragma unroll
        for (int kc = 0; kc < 16; ++kc) {
            bf16x8 b0 = __builtin_bit_cast(bf16x8, *(const u16x8v*)(u0 + HOFF + 32 * kc));
            acc0 = __builtin_amdgcn_mfma_f32_16x16x32_bf16(ahh[0][kc], b0, acc0, 0, 0, 0);
            acc1 = __builtin_amdgcn_mfma_f32_16x16x32_bf16(ahh[1][kc], b0, acc1, 0, 0, 0);
        }

        // ---- elementwise LSTM (lane-local: acc_m = i,f,g,o of unit 8wv+4m+q) ----
        {
            {
                float ig = sigmoidf_(acc0.x + bias[0][0]);
                float fg = sigmoidf_(acc0.y + bias[0][1]);
                float gg = tanhf_(acc0.z + bias[0][2]);
                float og = sigmoidf_(acc0.w + bias[0][3]);
                c0 = fg * c0 + ig * gg;
                h_scr[lm * SCR_S + 8 * wv + q] = f2bf(og * tanhf_(c0));
            }
            {
                float ig = sigmoidf_(acc1.x + bias[1][0]);
                float fg = sigmoidf_(acc1.y + bias[1][1]);
                float gg = tanhf_(acc1.z + bias[1][2]);
                float og = sigmoidf_(acc1.w + bias[1][3]);
                c1 = fg * c1 + ig * gg;
                h_scr[lm * SCR_S + 8 * wv + 4 + q] = f2bf(og * tanhf_(c1));
            }
        }
        __syncthreads();   // S3a: scratch complete (lgkmcnt drain)

        // ---- coalesced bypassing writeback: 128 x u64 (64B-contiguous per row) ----
        if (tid < 128) {
            const int r = tid >> 3;    // batch row 0..15
            const int d = tid & 7;     // u64 index 0..7 (4 units each)
            u64_t v = *(const u64_t*)((const char*)h_scr + r * (SCR_S * 2) + d * 8);
            ushort_t* hdst = hbuf + (size_t)((t + 1) & 1) * (256 * 512);
            g_store64((u64_t*)(hdst + (size_t)(Bg0 + r) * 512 + U0 + 4 * d), v);
        }
        __syncthreads();   // S3b: vmcnt(0) drain -> h stores at LLC before publish
        if (tid == 0) g_store_flag(&flags[g * 16 + ib], t + 2);
    }

    // ---- wait group done (513), then FC: block handles batch Bg0+ib ----
    if (wv == 0) {
        while (true) {
            int v = g_load_flag(myflag);
            if (__all(v >= 513)) break;
            __builtin_amdgcn_s_sleep(1);
        }
        asm volatile("" ::: "memory");
    }
    __syncthreads();

    {
        const int bb = Bg0 + ib;
        const ushort_t* hrow = hbuf + (size_t)bb * 512;  // final h in parity 0
        u64_t h0 = g_load64((const u64_t*)(hrow + lane * 8));
        u64_t h1 = g_load64((const u64_t*)(hrow + lane * 8 + 4));
        float hv[8];
#pragma unroll
        for (int j = 0; j < 4; ++j) hv[j]     = bf2f((ushort_t)(h0 >> (16 * j)));
#pragma unroll
        for (int j = 0; j < 4; ++j) hv[4 + j] = bf2f((ushort_t)(h1 >> (16 * j)));
#pragma unroll
        for (int oo = 0; oo < 2; ++oo) {
            int o = wv + 4 * oo;       // waves 0..3 -> o {0,4},{1,5},{2,6},{3}
            if (o < 7) {
                f32x4 w0 = *(const f32x4*)(Wfc + o * 512 + lane * 8);
                f32x4 w1 = *(const f32x4*)(Wfc + o * 512 + lane * 8 + 4);
                float s = hv[0] * w0.x + hv[1] * w0.y + hv[2] * w0.z + hv[3] * w0.w
                        + hv[4] * w1.x + hv[5] * w1.y + hv[6] * w1.z + hv[7] * w1.w;
#pragma unroll
                for (int sh = 32; sh >= 1; sh >>= 1) s += __shfl_down(s, sh);
                if (lane == 0)
                    out[bb * 7 + o] = s + bfc[o];
            }
        }
    }
}

extern "C" void kernel_launch(void* const* d_in, const int* in_sizes, int n_in,
                              void* d_out, int out_size, void* d_ws, size_t ws_size,
                              hipStream_t stream) {
    const int* tokens = (const int*)d_in[0];
    const float* emb  = (const float*)d_in[1];
    const float* Wih  = (const float*)d_in[2];
    const float* bih  = (const float*)d_in[3];
    const float* Whh  = (const float*)d_in[4];
    const float* bhh  = (const float*)d_in[5];
    const float* Wfc  = (const float*)d_in[6];
    const float* bfc  = (const float*)d_in[7];

    int* flags      = (int*)d_ws;                       // 256 ints (group g: flags[16g..16g+15])
    ushort_t* hbuf  = (ushort_t*)((char*)d_ws + 1024);  // [2][256][512] bf16 = 512 KiB

    lstm_fused_kernel<<<dim3(256), dim3(256), 0, stream>>>(
        tokens, emb, Wih, bih, Whh, bhh, Wfc, bfc,
        (float*)d_out, flags, hbuf);
}